// Round 4
// baseline (208.510 us; speedup 1.0000x reference)
//
#include <hip/hip_runtime.h>
#include <hip/hip_fp16.h>

#define B 8
#define H 160
#define W 160
#define D 96
#define S 64
#define ST_RATIO 1.5f

// ---------------------------------------------------------------------------
// Tier-1 prepass: vol [B,H,W,D] f32 -> volQ [B,H,D,W] ushort4 quads
//   quad(x,z,y) = fp16 { v(y,z), v(y+1,z), v(y,z+1), v(y+1,z+1) }  (clamped)
// One block per (b,h) plane: 240 KB contiguous read, LDS-staged, quad write.
// ---------------------------------------------------------------------------
__global__ __launch_bounds__(256) void v2s_quadprep(
    const float* __restrict__ vol, ushort4* __restrict__ volQ)
{
    __shared__ __half ph[W * 106];   // [w][d] rows padded to 106 halves = 53 words (odd -> conflict-free)
    const int bh = blockIdx.x;       // B*H = 1280 blocks
    const float* in = vol + (size_t)bh * (W * D);

    // stage plane f32 -> fp16 LDS, fully coalesced float4 reads
    for (int idx = threadIdx.x; idx < W * (D / 4); idx += 256) {
        const int w_ = idx / (D / 4), k = idx - w_ * (D / 4);
        const float4 f = *(const float4*)(in + w_ * D + 4 * k);
        __half2* dst = (__half2*)&ph[w_ * 106 + 4 * k];
        dst[0] = __floats2half2_rn(f.x, f.y);
        dst[1] = __floats2half2_rn(f.z, f.w);
    }
    __syncthreads();

    // build quads: out[d][w], lanes along w (coalesced 8B stores)
    ushort4* op = volQ + (size_t)bh * (D * W);
    for (int idx = threadIdx.x; idx < D * W; idx += 256) {
        const int d_ = idx / W, w_ = idx - d_ * W;
        const int w1 = min(w_ + 1, W - 1), d1 = min(d_ + 1, D - 1);
        ushort4 q;
        q.x = __half_as_ushort(ph[w_ * 106 + d_]);
        q.y = __half_as_ushort(ph[w1 * 106 + d_]);
        q.z = __half_as_ushort(ph[w_ * 106 + d1]);
        q.w = __half_as_ushort(ph[w1 * 106 + d1]);
        op[idx] = q;
    }
}

// ---------------------------------------------------------------------------
// Tier-1 main: 2 quad loads per sample. Wave = 64 hw-lanes at ONE s.
// ---------------------------------------------------------------------------
__global__ __launch_bounds__(256) void v2s_main_q(
    const ushort4* __restrict__ volQ,  // [B,H,D,W]
    const float*  __restrict__ trf,    // [B,S,12]
    float*        __restrict__ out)    // [B,H,W,S]
{
    __shared__ float As[S * 12];
    __shared__ float outT[64][65];

    const int bid  = blockIdx.x;
    const int tile = (bid & 7) * 400 + (bid >> 3);   // XCD swizzle: XCD <-> batch
    const int b    = tile / 400;
    const int hw0  = (tile - b * 400) * 64;

    const float* tb = trf + (size_t)b * (S * 12);
    for (int e = threadIdx.x; e < S * 12; e += 256) {
        const int j = e % 12;
        float v = tb[e];
        if ((j & 3) == (j >> 2)) v += 1.0f;
        As[e] = v;
    }
    __syncthreads();

    const int lane = threadIdx.x & 63;
    const int wid  = threadIdx.x >> 6;
    const int hw   = hw0 + lane;
    const int h    = hw / W;
    const int w    = hw - h * W;
    const float fh = (float)h, fw = (float)w;
    const ushort4* vb = volQ + (size_t)b * (H * D * W);

#pragma unroll 4
    for (int it = 0; it < 16; ++it) {
        const int s = it * 4 + wid;
        const float* a = &As[s * 12];
        const float fz = (float)s * ST_RATIO;

        float x = fmaf(a[0], fh, fmaf(a[1], fw, fmaf(a[2],  fz, a[3])));
        float y = fmaf(a[4], fh, fmaf(a[5], fw, fmaf(a[6],  fz, a[7])));
        float z = fmaf(a[8], fh, fmaf(a[9], fw, fmaf(a[10], fz, a[11])));

        x = fminf(fmaxf(x, 0.0f), (float)(H - 1));
        y = fminf(fmaxf(y, 0.0f), (float)(W - 1));
        z = fminf(fmaxf(z, 0.0f), (float)(D - 1));

        const float flx = floorf(x), fly = floorf(y), flz = floorf(z);
        const float dx = x - flx, dy = y - fly, dz = z - flz;
        const int ix0 = (int)flx, iy0 = (int)fly, iz0 = (int)flz;
        const int ix1 = min(ix0 + 1, H - 1);

        // quad holds y/y+1 and z/z+1 (pre-clamped) -> only x needs two loads
        const int base = iz0 * W + iy0;
        const ushort4 q0 = vb[ix0 * (D * W) + base];
        const ushort4 q1 = vb[ix1 * (D * W) + base];

        const float q0y0z0 = __half2float(__ushort_as_half(q0.x));
        const float q0y1z0 = __half2float(__ushort_as_half(q0.y));
        const float q0y0z1 = __half2float(__ushort_as_half(q0.z));
        const float q0y1z1 = __half2float(__ushort_as_half(q0.w));
        const float q1y0z0 = __half2float(__ushort_as_half(q1.x));
        const float q1y1z0 = __half2float(__ushort_as_half(q1.y));
        const float q1y0z1 = __half2float(__ushort_as_half(q1.z));
        const float q1y1z1 = __half2float(__ushort_as_half(q1.w));

        const float a00 = fmaf(dy, q0y1z0 - q0y0z0, q0y0z0);   // x0,z0
        const float a01 = fmaf(dy, q0y1z1 - q0y0z1, q0y0z1);   // x0,z1
        const float a10 = fmaf(dy, q1y1z0 - q1y0z0, q1y0z0);   // x1,z0
        const float a11 = fmaf(dy, q1y1z1 - q1y0z1, q1y0z1);   // x1,z1
        const float e0  = fmaf(dz, a01 - a00, a00);
        const float e1  = fmaf(dz, a11 - a10, a10);
        outT[lane][s]   = fmaf(dx, e1 - e0, e0);
    }
    __syncthreads();

    const int s_out = lane;
#pragma unroll
    for (int r = 0; r < 16; ++r) {
        const int hw_off = wid + 4 * r;
        out[((size_t)(b * (H * W) + hw0 + hw_off)) * S + s_out] = outT[hw_off][s_out];
    }
}

// ---------------------------------------------------------------------------
// Tier-2 (R2 path): fp16 transpose + 8-load main. Used if ws < quad size.
// ---------------------------------------------------------------------------
__global__ __launch_bounds__(256) void v2s_transpose(
    const float* __restrict__ vol, __half* __restrict__ volT)
{
    __shared__ float t[32][33];
    const int blk = blockIdx.x;
    const int bh  = blk / 15;
    const int rem = blk - bh * 15;
    const int wt  = rem / 3;
    const int dt  = rem - wt * 3;
    const float* in  = vol  + (size_t)bh * (W * D);
    __half*      op  = volT + (size_t)bh * (D * W);
    const int tx = threadIdx.x & 31, ty = threadIdx.x >> 5;
#pragma unroll
    for (int r = 0; r < 4; ++r) {
        t[ty + 8 * r][tx] = in[(wt * 32 + ty + 8 * r) * D + dt * 32 + tx];
    }
    __syncthreads();
#pragma unroll
    for (int r = 0; r < 4; ++r) {
        op[(dt * 32 + ty + 8 * r) * W + wt * 32 + tx] = __float2half(t[tx][ty + 8 * r]);
    }
}

__global__ __launch_bounds__(256) void v2s_main(
    const __half* __restrict__ volT, const float* __restrict__ trf,
    float* __restrict__ out)
{
    __shared__ float As[S * 12];
    __shared__ float outT[64][65];
    const int bid  = blockIdx.x;
    const int tile = (bid & 7) * 400 + (bid >> 3);
    const int b    = tile / 400;
    const int hw0  = (tile - b * 400) * 64;
    const float* tb = trf + (size_t)b * (S * 12);
    for (int e = threadIdx.x; e < S * 12; e += 256) {
        const int j = e % 12;
        float v = tb[e];
        if ((j & 3) == (j >> 2)) v += 1.0f;
        As[e] = v;
    }
    __syncthreads();
    const int lane = threadIdx.x & 63;
    const int wid  = threadIdx.x >> 6;
    const int hw   = hw0 + lane;
    const int h    = hw / W;
    const int w    = hw - h * W;
    const float fh = (float)h, fw = (float)w;
    const __half* vb = volT + (size_t)b * (H * D * W);
#pragma unroll 4
    for (int it = 0; it < 16; ++it) {
        const int s = it * 4 + wid;
        const float* a = &As[s * 12];
        const float fz = (float)s * ST_RATIO;
        float x = fmaf(a[0], fh, fmaf(a[1], fw, fmaf(a[2],  fz, a[3])));
        float y = fmaf(a[4], fh, fmaf(a[5], fw, fmaf(a[6],  fz, a[7])));
        float z = fmaf(a[8], fh, fmaf(a[9], fw, fmaf(a[10], fz, a[11])));
        x = fminf(fmaxf(x, 0.0f), (float)(H - 1));
        y = fminf(fmaxf(y, 0.0f), (float)(W - 1));
        z = fminf(fmaxf(z, 0.0f), (float)(D - 1));
        const float flx = floorf(x), fly = floorf(y), flz = floorf(z);
        const float dx = x - flx, dy = y - fly, dz = z - flz;
        const int ix0 = (int)flx, iy0 = (int)fly, iz0 = (int)flz;
        const int ix1 = min(ix0 + 1, H - 1);
        const int iy1 = min(iy0 + 1, W - 1);
        const int iz1 = min(iz0 + 1, D - 1);
        const __half* p00 = vb + (ix0 * D + iz0) * W;
        const __half* p01 = vb + (ix0 * D + iz1) * W;
        const __half* p10 = vb + (ix1 * D + iz0) * W;
        const __half* p11 = vb + (ix1 * D + iz1) * W;
        const float v000 = __half2float(p00[iy0]), v001 = __half2float(p00[iy1]);
        const float v010 = __half2float(p01[iy0]), v011 = __half2float(p01[iy1]);
        const float v100 = __half2float(p10[iy0]), v101 = __half2float(p10[iy1]);
        const float v110 = __half2float(p11[iy0]), v111 = __half2float(p11[iy1]);
        const float c00 = fmaf(dy, v001 - v000, v000);
        const float c01 = fmaf(dy, v011 - v010, v010);
        const float c10 = fmaf(dy, v101 - v100, v100);
        const float c11 = fmaf(dy, v111 - v110, v110);
        const float c0  = fmaf(dz, c01 - c00, c00);
        const float c1  = fmaf(dz, c11 - c10, c10);
        outT[lane][s]   = fmaf(dx, c1 - c0, c0);
    }
    __syncthreads();
    const int s_out = lane;
#pragma unroll
    for (int r = 0; r < 16; ++r) {
        const int hw_off = wid + 4 * r;
        out[((size_t)(b * (H * W) + hw0 + hw_off)) * S + s_out] = outT[hw_off][s_out];
    }
}

// Tier-3 fallback: direct f32 gather (R1).
__global__ __launch_bounds__(256) void v2s_fallback(
    const float* __restrict__ vol, const float* __restrict__ trf,
    float* __restrict__ out)
{
    __shared__ float As[S * 13];
    const int pos0 = blockIdx.x * 4;
    const int b = pos0 / (H * W);
    const float* tb = trf + (size_t)b * S * 12;
    for (int e = threadIdx.x; e < S * 12; e += 256) {
        int s = e / 12, j = e - s * 12;
        float v = tb[e];
        if ((j & 3) == (j >> 2)) v += 1.0f;
        As[s * 13 + j] = v;
    }
    __syncthreads();
    const int s   = threadIdx.x & 63;
    const int pos = pos0 + (threadIdx.x >> 6);
    const int hw  = pos % (H * W);
    const int h   = hw / W;
    const int w   = hw - h * W;
    const float* a = &As[s * 13];
    const float fh = (float)h, fw = (float)w, fz = (float)s * ST_RATIO;
    float x = fmaf(a[0], fh, fmaf(a[1], fw, fmaf(a[2],  fz, a[3])));
    float y = fmaf(a[4], fh, fmaf(a[5], fw, fmaf(a[6],  fz, a[7])));
    float z = fmaf(a[8], fh, fmaf(a[9], fw, fmaf(a[10], fz, a[11])));
    x = fminf(fmaxf(x, 0.0f), (float)(H - 1));
    y = fminf(fmaxf(y, 0.0f), (float)(W - 1));
    z = fminf(fmaxf(z, 0.0f), (float)(D - 1));
    const float flx = floorf(x), fly = floorf(y), flz = floorf(z);
    const float dx = x - flx, dy = y - fly, dz = z - flz;
    const int ix0 = (int)flx, iy0 = (int)fly, iz0 = (int)flz;
    const int ix1 = min(ix0 + 1, H - 1);
    const int iy1 = min(iy0 + 1, W - 1);
    const int iz1 = min(iz0 + 1, D - 1);
    const float* vb  = vol + (size_t)b * (H * W * D);
    const float* p00 = vb + (ix0 * W + iy0) * D;
    const float* p01 = vb + (ix0 * W + iy1) * D;
    const float* p10 = vb + (ix1 * W + iy0) * D;
    const float* p11 = vb + (ix1 * W + iy1) * D;
    const float v000 = p00[iz0], v001 = p00[iz1];
    const float v010 = p01[iz0], v011 = p01[iz1];
    const float v100 = p10[iz0], v101 = p10[iz1];
    const float v110 = p11[iz0], v111 = p11[iz1];
    const float c00 = fmaf(dz, v001 - v000, v000);
    const float c01 = fmaf(dz, v011 - v010, v010);
    const float c10 = fmaf(dz, v101 - v100, v100);
    const float c11 = fmaf(dz, v111 - v110, v110);
    const float c0  = fmaf(dy, c01 - c00, c00);
    const float c1  = fmaf(dy, c11 - c10, c10);
    out[(size_t)pos * S + s] = fmaf(dx, c1 - c0, c0);
}

extern "C" void kernel_launch(void* const* d_in, const int* in_sizes, int n_in,
                              void* d_out, int out_size, void* d_ws, size_t ws_size,
                              hipStream_t stream) {
    const float* vol = (const float*)d_in[0];
    const float* trf = (const float*)d_in[1];
    float* out = (float*)d_out;

    const size_t quad_bytes = (size_t)B * H * D * W * sizeof(ushort4);  // 157.3 MB
    const size_t volT_bytes = (size_t)B * H * D * W * sizeof(__half);   //  39.3 MB
    if (ws_size >= quad_bytes) {
        ushort4* volQ = (ushort4*)d_ws;
        v2s_quadprep<<<B * H, 256, 0, stream>>>(vol, volQ);
        v2s_main_q<<<(B * H * W) / 64, 256, 0, stream>>>(volQ, trf, out);
    } else if (ws_size >= volT_bytes) {
        __half* volT = (__half*)d_ws;
        v2s_transpose<<<B * H * 5 * 3, 256, 0, stream>>>(vol, volT);
        v2s_main<<<(B * H * W) / 64, 256, 0, stream>>>(volT, trf, out);
    } else {
        v2s_fallback<<<(B * H * W) / 4, 256, 0, stream>>>(vol, trf, out);
    }
}